// Round 13
// baseline (53.064 us; speedup 1.0000x reference)
//
#include <hip/hip_runtime.h>
#include <math.h>

constexpr int kN = 65536;
constexpr int kB = 16384;
constexpr int kNB = 1024;        // buckets by g>>6; bucket 1023 -> cold list
constexpr int kBufW = 8192;      // 128 rows x 64 words
constexpr int kColdCap = 512;
constexpr int kTileW = 2560;     // cold kernel: tiered packed triangle

static __device__ __forceinline__ float bcastf(float v, int lane) {
    union { float f; int i; } u;
    u.f = v;
    u.i = __builtin_amdgcn_readlane(u.i, lane);
    return u.f;
}

static __device__ __forceinline__ void gload_lds16(const float* g, float* l) {
    __builtin_amdgcn_global_load_lds(
        (const __attribute__((address_space(1))) void*)g,
        (__attribute__((address_space(3))) void*)l, 16, 0, 0);
}
static __device__ __forceinline__ void gload_lds4(const float* g, float* l) {
    __builtin_amdgcn_global_load_lds(
        (const __attribute__((address_space(1))) void*)g,
        (__attribute__((address_space(3))) void*)l, 4, 0, 0);
}

static __device__ __forceinline__ int row_start(int j) {   // cold tiered layout
    const int t = j >> 4;
    return 1024 * t - 128 * t * (t - 1) + (64 - 16 * t) * (j - 16 * t);
}
static __device__ __forceinline__ bool is_hot(int g) {
    return (g >= 63) && (g <= kN - 63);
}

// ---------------- kernel A: bucket sort (one block) ----------------
__global__ __launch_bounds__(1024) void gp_sort_kernel(
    const int* __restrict__ gidx,
    int* __restrict__ sortedg, int* __restrict__ start,
    int* __restrict__ coldg, int* __restrict__ coldcnt)
{
    __shared__ int hist[kNB];
    __shared__ int wsum[16];
    __shared__ int coldc;
    const int t = (int)threadIdx.x, lane = t & 63, w = t >> 6;
    hist[t] = 0;
    if (t == 0) coldc = 0;
    __syncthreads();
    int gs[16];
    #pragma unroll
    for (int k = 0; k < 16; ++k) {
        gs[k] = gidx[t + 1024 * k];
        const int bkt = gs[k] >> 6;
        if (bkt < kNB - 1) atomicAdd(&hist[bkt], 1);
    }
    __syncthreads();
    const int v = hist[t];
    int x = v;
    #pragma unroll
    for (int d = 1; d < 64; d <<= 1) {
        const int nn = __shfl_up(x, d, 64);
        if (lane >= d) x += nn;
    }
    if (lane == 63) wsum[w] = x;
    __syncthreads();
    if (t == 0) {
        int acc = 0;
        #pragma unroll
        for (int k = 0; k < 16; ++k) { const int sv = wsum[k]; wsum[k] = acc; acc += sv; }
    }
    __syncthreads();
    const int excl = x - v + wsum[w];         // exclusive prefix over buckets
    start[t] = excl;
    if (t == kNB - 1) start[kNB] = excl + v;  // total hot count
    __syncthreads();
    hist[t] = excl;                           // reuse as scatter cursor
    __syncthreads();
    #pragma unroll
    for (int k = 0; k < 16; ++k) {
        const int g = gs[k], bkt = g >> 6;
        if (bkt < kNB - 1) {
            const int p = atomicAdd(&hist[bkt], 1);
            sortedg[p] = g;
        } else {
            const int p = atomicAdd(&coldc, 1);
            if (p < kColdCap) coldg[p] = g;
        }
    }
    __syncthreads();
    if (t == 0) coldcnt[0] = (coldc < kColdCap) ? coldc : kColdCap;
}

// ---------------- kernel B: hot buckets, shared union tile ----------------
__global__ __launch_bounds__(256) void gp_bucket_kernel(
    const float* __restrict__ Uv,
    const float* __restrict__ Vv,
    const float* __restrict__ mean,
    const float* __restrict__ mean_post,
    const float* __restrict__ y,
    const int*   __restrict__ crow_u,
    const float* __restrict__ noise,
    const int*   __restrict__ sortedg,
    const int*   __restrict__ start,
    float*       __restrict__ partial)
{
    // rows r in [64b-63, 64b+64], stride 64 words: ONE contiguous Vv block.
    __shared__ __align__(16) float buf[kBufW];
    __shared__ float cred[4];

    const int tid  = (int)threadIdx.x, lane = tid & 63, wid = tid >> 6;
    const int bid  = (int)blockIdx.x;
    const int b    = ((bid & 7) << 7) | (bid >> 3);   // chunked XCD swizzle
    const int s    = start[b];
    const int n    = start[b + 1] - s;
    if (n == 0) { if (tid == 0) partial[b] = 0.0f; return; }

    const float inv2n = 0.5f / noise[0];

    if (b > 0) {
        // crow_v[r] = 64r throughout the band for b <= 1022: stage 32KB
        // linearly. LDS dest must be WAVE-UNIFORM (HW adds lane*16B itself).
        const float* src = Vv + 64 * (64 * b - 63);
        #pragma unroll
        for (int k = 0; k < 8; ++k) {
            const int ow = 1024 * k + 256 * wid;      // wave-uniform offset
            gload_lds16(src + ow + 4 * lane, buf + ow);
        }
    } else {
        // bucket 0 (one block, cold-ish): plain loads + ds_write -- no DMA
        // placement subtleties. Rows r<0 (words < 63*64=4032) are zero.
        #pragma unroll
        for (int k = 0; k < 8; ++k) {
            const int wd = 1024 * k + 4 * tid;
            float4 val = make_float4(0.0f, 0.0f, 0.0f, 0.0f);
            if (wd >= 4032)
                val = *reinterpret_cast<const float4*>(Vv + (wd - 4032));
            *reinterpret_cast<float4*>(buf + wd) = val;
        }
    }
    asm volatile("s_waitcnt vmcnt(0) lgkmcnt(0)" ::: "memory");
    __syncthreads();   // all waves' staging drained before shared reads

    float accum = 0.0f;
    for (int e = wid; e < n; e += 4) {            // waves share the bucket
        const int g   = sortedg[s + e];
        const int off = g - 64 * b;               // 0..63
        const int anc = g - 63 + lane;
        const bool vl = (anc >= 0);
        const int  L  = (g + 1 < 64) ? (g + 1) : 64;
        const int  ub = (g >= 63) ? (2016 + 64 * (g - 63)) : crow_u[g];

        float uval = 0.0f, md = 0.0f;
        if (vl) {
            uval = Uv[ub + lane - (64 - L)];
            md   = mean[anc] - mean_post[anc];
        }
        const float yv  = y[g];
        const float mpv = mean_post[g];

        const int l = off + lane;                 // this lane's LDS row
        const float d0 = buf[64 * l];
        // invalid lanes (bucket 0, anc<0): identity rows, mask via invd=0
        const float invd = vl ? (1.0f / d0) : 0.0f;

        // v[i] = V_sub[lane][i]/diag = buf[64l + i - lane]/diag; i<lane reads
        // prior-row tail (finite, provably unused before consumption at i=lane).
        const float* vrow = buf + (64 * l - lane);
        float v[64];
        #pragma unroll
        for (int i = 0; i < 64; i += 2) {         // ds_read2 pairs
            const float a0 = vrow[i];
            const float a1 = vrow[i + 1];
            v[i]     = a0 * invd;
            v[i + 1] = a1 * invd;
        }

        float r_e = (lane == 63) ? invd : 0.0f;   // lane 63 always valid
        float r_u = uval * invd;
        float acc_e = 0.0f, acc_u = 0.0f;
        #pragma unroll
        for (int i = 63; i >= 0; --i) {
            const float s_e = bcastf(r_e, i);
            const float s_u = bcastf(r_u, i);
            r_e = fmaf(-v[i], s_e, r_e);
            r_u = fmaf(-v[i], s_u, r_u);
            acc_e = fmaf(s_e, s_e, acc_e);
            acc_u = fmaf(s_u, s_u, acc_u);
        }

        float dot = uval * md;
        #pragma unroll
        for (int m = 1; m < 64; m <<= 1)
            dot += __shfl_xor(dot, m, 64);

        const float ulast  = bcastf(uval, 63);
        const float vfirst = bcastf(d0, 63);      // lane63 row = g -> V[crow_v[g]]
        const float resid  = yv - mpv;
        accum += __logf(ulast) - __logf(vfirst)
               - 0.5f * dot * dot
               - 0.5f * acc_u
               - (resid * resid + acc_e) * inv2n;
    }

    if (lane == 0) cred[wid] = accum;
    __syncthreads();
    if (tid == 0)
        partial[b] = (cred[0] + cred[1]) + (cred[2] + cred[3]);
}

// ---------------- kernel C: cold elements (bucket 1023) ----------------
__global__ __launch_bounds__(64) void gp_cold_kernel(
    const float* __restrict__ Uv,
    const float* __restrict__ Vv,
    const float* __restrict__ mean,
    const float* __restrict__ mean_post,
    const float* __restrict__ y,
    const int*   __restrict__ crow_u,
    const int*   __restrict__ crow_v,
    const float* __restrict__ noise,
    const int*   __restrict__ coldg,
    const int*   __restrict__ coldcnt,
    float*       __restrict__ partialC)
{
    __shared__ __align__(16) float myl[kTileW];
    const int lane = (int)threadIdx.x;
    const int i    = (int)blockIdx.x;
    const int cnt  = coldcnt[0];
    if (i >= cnt) { if (lane == 0) partialC[i] = 0.0f; return; }
    const int g = coldg[i];

    const int  anc = g - 63 + lane;
    const bool vl  = (anc >= 0);
    const int  L   = (g + 1 < 64) ? (g + 1) : 64;
    const int  ub  = (g >= 63) ? (2016 + 64 * (g - 63)) : crow_u[g];

    float uval = 0.0f, md = 0.0f;
    if (vl) {
        uval = Uv[ub + lane - (64 - L)];
        md   = mean[anc] - mean_post[anc];
    }
    const float yg  = y[g];
    const float mpg = mean_post[g];

    if (is_hot(g)) {
        const float* base = Vv + 64 * (g - 63);
        { const float* src = base + 4 * lane;
          #pragma unroll
          for (int k = 0; k < 4; ++k) gload_lds16(src + 256 * k, myl + 256 * k); }
        #pragma unroll
        for (int k = 0; k < 3; ++k) {
            const int w   = 256 * k + 4 * lane;
            const int jj  = ((w >> 4) * 171) >> 9;
            const int col = w - 48 * jj;
            gload_lds16(base + 64 * (16 + jj) + col, myl + 1024 + 256 * k);
        }
        #pragma unroll
        for (int k = 0; k < 2; ++k) {
            const int w = 256 * k + 4 * lane;
            gload_lds16(base + 64 * (32 + (w >> 5)) + (w & 31), myl + 1792 + 256 * k);
        }
        { const int w = 4 * lane;
          gload_lds16(base + 64 * (48 + (w >> 4)) + (w & 15), myl + 2304); }
    } else {
        int rowbase = 0;
        if (vl) rowbase = crow_v[anc];
        for (int j = 0; j < 64; ++j) {
            const int rbj = __builtin_amdgcn_readlane(rowbase, j);
            const int dst = row_start(j);
            if (lane < 64 - j) {
                if (g - 63 + j >= 0) gload_lds4(Vv + rbj + lane, myl + dst);
                else                 myl[dst + lane] = 0.0f;
            }
        }
    }
    asm volatile("s_waitcnt vmcnt(0) lgkmcnt(0)" ::: "memory");

    const int rs = row_start(lane);
    const float d0   = myl[rs];
    const float diag = vl ? d0 : 1.0f;
    const float invd = vl ? (1.0f / d0) : 0.0f;

    const float* vrow = myl + (rs - lane);
    float v[64];
    #pragma unroll
    for (int i2 = 0; i2 < 64; i2 += 2) {
        const float a0 = vrow[i2];
        const float a1 = vrow[i2 + 1];
        v[i2]     = a0 * invd;
        v[i2 + 1] = a1 * invd;
    }

    float r_e = (lane == 63) ? invd : 0.0f;
    float r_u = uval * invd;
    float acc_e = 0.0f, acc_u = 0.0f;
    #pragma unroll
    for (int i2 = 63; i2 >= 0; --i2) {
        const float s_e = bcastf(r_e, i2);
        const float s_u = bcastf(r_u, i2);
        r_e = fmaf(-v[i2], s_e, r_e);
        r_u = fmaf(-v[i2], s_u, r_u);
        acc_e = fmaf(s_e, s_e, acc_e);
        acc_u = fmaf(s_u, s_u, acc_u);
    }

    float dot = uval * md;
    #pragma unroll
    for (int m = 1; m < 64; m <<= 1)
        dot += __shfl_xor(dot, m, 64);

    const float ulast  = bcastf(uval, 63);
    const float vfirst = bcastf(diag, 63);
    if (lane == 0) {
        const float resid = yg - mpg;
        const float inv2n = 0.5f / noise[0];
        partialC[i] = __logf(ulast) - __logf(vfirst)
                    - 0.5f * dot * dot
                    - 0.5f * acc_u
                    - (resid * resid + acc_e) * inv2n;
    }
}

// ---------------- kernel D: final reduce ----------------
__global__ __launch_bounds__(512) void gp_reduce_kernel(
    const float* __restrict__ partials,   // partial[1024] ++ partialC[512]
    const float* __restrict__ noise,
    float*       __restrict__ out)
{
    __shared__ float ws[8];
    const int t = (int)threadIdx.x;
    float a = 0.0f;
    if (t < 384) {                        // 1536 floats = 384 float4
        const float4 p = reinterpret_cast<const float4*>(partials)[t];
        a = (p.x + p.y) + (p.z + p.w);
    }
    #pragma unroll
    for (int m = 1; m < 64; m <<= 1)
        a += __shfl_xor(a, m, 64);
    if ((t & 63) == 0) ws[t >> 6] = a;
    __syncthreads();
    if (t == 0) {
        float tot = 0.0f;
        #pragma unroll
        for (int k = 0; k < 8; ++k) tot += ws[k];
        tot += -0.5f * (float)kB * logf(2.0f * 3.14159265358979323846f * noise[0]);
        out[0] = tot;
    }
}

extern "C" void kernel_launch(void* const* d_in, const int* in_sizes, int n_in,
                              void* d_out, int out_size, void* d_ws, size_t ws_size,
                              hipStream_t stream)
{
    const float* Uv        = (const float*)d_in[0];
    const float* Vv        = (const float*)d_in[1];
    const float* mean      = (const float*)d_in[2];
    const float* mean_post = (const float*)d_in[3];
    const float* y         = (const float*)d_in[4];
    const float* noise     = (const float*)d_in[5];
    const int*   gidx      = (const int*)d_in[6];
    const int*   crow_u    = (const int*)d_in[7];
    const int*   crow_v    = (const int*)d_in[8];

    // ws (ints): sortedg[16384] | start[1025] | coldg[512] | coldcnt[1] |
    //            pad | partial[1024]f ++ partialC[512]f   (16B aligned)
    int* ws_i      = (int*)d_ws;
    int* sortedg   = ws_i;
    int* start     = ws_i + 16384;
    int* coldg     = ws_i + 16384 + 1025;
    int* coldcnt   = ws_i + 16384 + 1025 + 512;
    float* partial  = (float*)(ws_i + 17924);       // 71696 B, 16B aligned
    float* partialC = partial + kNB;

    gp_sort_kernel<<<dim3(1), dim3(1024), 0, stream>>>(
        gidx, sortedg, start, coldg, coldcnt);
    gp_bucket_kernel<<<dim3(kNB), dim3(256), 0, stream>>>(
        Uv, Vv, mean, mean_post, y, crow_u, noise, sortedg, start, partial);
    gp_cold_kernel<<<dim3(kColdCap), dim3(64), 0, stream>>>(
        Uv, Vv, mean, mean_post, y, crow_u, crow_v, noise, coldg, coldcnt, partialC);
    gp_reduce_kernel<<<dim3(1), dim3(512), 0, stream>>>(
        partial, noise, (float*)d_out);
}

// Round 14
// 49.126 us; speedup vs baseline: 1.0802x; 1.0802x over previous
//
#include <hip/hip_runtime.h>
#include <math.h>

constexpr int kN = 65536;
constexpr int kB = 16384;
constexpr int kNB = 1024;        // buckets by g>>6 (all real, incl. 1023 tail)
constexpr int kBufW = 8192;      // 128 rows x 64 words

static __device__ __forceinline__ float bcastf(float v, int lane) {
    union { float f; int i; } u;
    u.f = v;
    u.i = __builtin_amdgcn_readlane(u.i, lane);
    return u.f;
}

static __device__ __forceinline__ void gload_lds16(const float* g, float* l) {
    __builtin_amdgcn_global_load_lds(
        (const __attribute__((address_space(1))) void*)g,
        (__attribute__((address_space(3))) void*)l, 16, 0, 0);
}

// ---------------- kernel A1: histogram (16 blocks) ----------------
__global__ __launch_bounds__(1024) void gp_hist_kernel(
    const int* __restrict__ gidx, int* __restrict__ hist)
{
    const int i = (int)blockIdx.x * 1024 + (int)threadIdx.x;
    atomicAdd(&hist[gidx[i] >> 6], 1);
}

// ---------------- kernel A2: scan (1 block); hist becomes scatter cursor ----
__global__ __launch_bounds__(1024) void gp_scan_kernel(
    int* __restrict__ hist, int* __restrict__ start)
{
    __shared__ int wsum[16];
    const int t = (int)threadIdx.x, lane = t & 63, w = t >> 6;
    const int v = hist[t];
    int x = v;
    #pragma unroll
    for (int d = 1; d < 64; d <<= 1) {
        const int nn = __shfl_up(x, d, 64);
        if (lane >= d) x += nn;
    }
    if (lane == 63) wsum[w] = x;
    __syncthreads();
    if (t == 0) {
        int acc = 0;
        #pragma unroll
        for (int k = 0; k < 16; ++k) { const int sv = wsum[k]; wsum[k] = acc; acc += sv; }
    }
    __syncthreads();
    const int excl = x - v + wsum[w];        // exclusive prefix
    start[t] = excl;
    if (t == kNB - 1) start[kNB] = excl + v; // = kB
    hist[t] = excl;                          // reuse as scatter cursor
}

// ---------------- kernel A3: scatter (16 blocks) ----------------
__global__ __launch_bounds__(1024) void gp_scatter_kernel(
    const int* __restrict__ gidx, int* __restrict__ cursor,
    int* __restrict__ sortedg)
{
    const int i = (int)blockIdx.x * 1024 + (int)threadIdx.x;
    const int g = gidx[i];
    const int p = atomicAdd(&cursor[g >> 6], 1);
    sortedg[p] = g;
}

// ---------------- kernel B: buckets with shared union band ----------------
__global__ __launch_bounds__(256) void gp_bucket_kernel(
    const float* __restrict__ Uv,
    const float* __restrict__ Vv,
    const float* __restrict__ mean,
    const float* __restrict__ mean_post,
    const float* __restrict__ y,
    const int*   __restrict__ crow_u,
    const int*   __restrict__ crow_v,
    const float* __restrict__ noise,
    const int*   __restrict__ sortedg,
    const int*   __restrict__ start,
    float*       __restrict__ partial)
{
    // band rows r in [64b-63, 64b+64], LDS stride 64 words.
    __shared__ __align__(16) float buf[kBufW];
    __shared__ float cred[4];

    const int tid  = (int)threadIdx.x, lane = tid & 63, wid = tid >> 6;
    const int bid  = (int)blockIdx.x;
    const int b    = ((bid & 7) << 7) | (bid >> 3);   // XCD-chunked (bijective)
    const int s    = start[b];
    const int n    = start[b + 1] - s;
    if (n == 0) { if (tid == 0) partial[b] = 0.0f; return; }

    const float inv2n = 0.5f / noise[0];

    if (b >= 1 && b <= kNB - 2) {
        // crow_v[r] = 64r across the whole band: one contiguous 32KB block.
        // LDS dest must be WAVE-UNIFORM (HW places lane L at dest + 16L).
        const float* src = Vv + 64 * (64 * b - 63);
        #pragma unroll
        for (int k = 0; k < 8; ++k) {
            const int ow = 1024 * k + 256 * wid;      // wave-uniform
            gload_lds16(src + ow + 4 * lane, buf + ow);
        }
    } else if (b == 0) {
        // rows r<0 (words < 63*64=4032) are identity -> zero; plain loads.
        #pragma unroll
        for (int k = 0; k < 8; ++k) {
            const int wd = 1024 * k + 4 * tid;
            float4 val = make_float4(0.0f, 0.0f, 0.0f, 0.0f);
            if (wd >= 4032)
                val = *reinterpret_cast<const float4*>(Vv + (wd - 4032));
            *reinterpret_cast<float4*>(buf + wd) = val;
        }
    } else {
        // b == 1023: band tail, crow_v irregular past r=65473. Stage per-row;
        // consumed columns (<= g <= N-1) always lie within the valid width.
        for (int j = wid; j < 127; j += 4) {
            const int r  = 64 * (kNB - 1) - 63 + j;   // 65409 + j
            const int rb = crow_v[r];                 // uniform per wave-iter
            const int w  = (kN - r < 64) ? (kN - r) : 64;
            const float val = (lane < w) ? Vv[rb + lane] : 0.0f;
            buf[64 * j + lane] = val;
        }
    }
    asm volatile("s_waitcnt vmcnt(0) lgkmcnt(0)" ::: "memory");
    __syncthreads();   // all waves' staging visible before shared reads

    float accum = 0.0f;
    for (int e = wid; e < n; e += 4) {            // waves share the bucket
        const int g   = sortedg[s + e];
        const int off = g - 64 * b;               // 0..63
        const int anc = g - 63 + lane;
        const bool vl = (anc >= 0);               // false only in bucket 0
        const int  L  = (g + 1 < 64) ? (g + 1) : 64;
        const int  ub = (g >= 63) ? (2016 + 64 * (g - 63)) : crow_u[g];

        float uval = 0.0f, md = 0.0f;
        if (vl) {
            uval = Uv[ub + lane - (64 - L)];
            md   = mean[anc] - mean_post[anc];
        }
        const float yv  = y[g];
        const float mpv = mean_post[g];

        const int l = off + lane;                 // this lane's LDS band row
        const float d0 = buf[64 * l];
        const float invd = vl ? (1.0f / d0) : 0.0f;   // mask identity rows

        // v[i] = V_sub[lane][i]/diag = buf[64l + i - lane]/diag; i<lane hits
        // prior-row tail (dead before this lane's residual is consumed).
        const float* vrow = buf + (64 * l - lane);
        float v[64];
        #pragma unroll
        for (int i = 0; i < 64; i += 2) {         // ds_read2 pairs
            const float a0 = vrow[i];
            const float a1 = vrow[i + 1];
            v[i]     = a0 * invd;
            v[i + 1] = a1 * invd;
        }

        float r_e = (lane == 63) ? invd : 0.0f;   // lane 63 always valid
        float r_u = uval * invd;
        float acc_e = 0.0f, acc_u = 0.0f;
        #pragma unroll
        for (int i = 63; i >= 0; --i) {
            const float s_e = bcastf(r_e, i);
            const float s_u = bcastf(r_u, i);
            r_e = fmaf(-v[i], s_e, r_e);
            r_u = fmaf(-v[i], s_u, r_u);
            acc_e = fmaf(s_e, s_e, acc_e);
            acc_u = fmaf(s_u, s_u, acc_u);
        }

        float dot = uval * md;
        #pragma unroll
        for (int m = 1; m < 64; m <<= 1)
            dot += __shfl_xor(dot, m, 64);

        const float ulast  = bcastf(uval, 63);
        const float vfirst = bcastf(d0, 63);      // lane63 row = g
        const float resid  = yv - mpv;
        accum += __logf(ulast) - __logf(vfirst)
               - 0.5f * dot * dot
               - 0.5f * acc_u
               - (resid * resid + acc_e) * inv2n;
    }

    if (lane == 0) cred[wid] = accum;
    __syncthreads();
    if (tid == 0)
        partial[b] = (cred[0] + cred[1]) + (cred[2] + cred[3]);
}

// ---------------- kernel C: final reduce ----------------
__global__ __launch_bounds__(256) void gp_reduce_kernel(
    const float* __restrict__ partial,    // [1024]
    const float* __restrict__ noise,
    float*       __restrict__ out)
{
    __shared__ float ws[4];
    const int t = (int)threadIdx.x;
    const float4 p = reinterpret_cast<const float4*>(partial)[t];  // 256*4=1024
    float a = (p.x + p.y) + (p.z + p.w);
    #pragma unroll
    for (int m = 1; m < 64; m <<= 1)
        a += __shfl_xor(a, m, 64);
    if ((t & 63) == 0) ws[t >> 6] = a;
    __syncthreads();
    if (t == 0) {
        float tot = (ws[0] + ws[1]) + (ws[2] + ws[3]);
        tot += -0.5f * (float)kB * logf(2.0f * 3.14159265358979323846f * noise[0]);
        out[0] = tot;
    }
}

extern "C" void kernel_launch(void* const* d_in, const int* in_sizes, int n_in,
                              void* d_out, int out_size, void* d_ws, size_t ws_size,
                              hipStream_t stream)
{
    const float* Uv        = (const float*)d_in[0];
    const float* Vv        = (const float*)d_in[1];
    const float* mean      = (const float*)d_in[2];
    const float* mean_post = (const float*)d_in[3];
    const float* y         = (const float*)d_in[4];
    const float* noise     = (const float*)d_in[5];
    const int*   gidx      = (const int*)d_in[6];
    const int*   crow_u    = (const int*)d_in[7];
    const int*   crow_v    = (const int*)d_in[8];

    // ws (ints): sortedg[16384] | hist/cursor[1024] | start[1025] | pad |
    //            partial[1024]f   (16B aligned at 18448)
    int* ws_i     = (int*)d_ws;
    int* sortedg  = ws_i;
    int* hist     = ws_i + 16384;
    int* start    = ws_i + 16384 + 1024;
    float* partial = (float*)(ws_i + 18448);      // 73792 B offset, 16B aligned

    hipMemsetAsync(hist, 0, kNB * sizeof(int), stream);
    gp_hist_kernel   <<<dim3(kB / 1024), dim3(1024), 0, stream>>>(gidx, hist);
    gp_scan_kernel   <<<dim3(1),         dim3(1024), 0, stream>>>(hist, start);
    gp_scatter_kernel<<<dim3(kB / 1024), dim3(1024), 0, stream>>>(gidx, hist, sortedg);
    gp_bucket_kernel <<<dim3(kNB),       dim3(256),  0, stream>>>(
        Uv, Vv, mean, mean_post, y, crow_u, crow_v, noise, sortedg, start, partial);
    gp_reduce_kernel <<<dim3(1),         dim3(256),  0, stream>>>(
        partial, noise, (float*)d_out);
}

// Round 15
// 46.707 us; speedup vs baseline: 1.1361x; 1.0518x over previous
//
#include <hip/hip_runtime.h>
#include <math.h>

constexpr int kN = 65536;
constexpr int kB = 16384;
constexpr int kNB = 1024;        // buckets by g>>6; block b owns bucket b
constexpr int kBufW = 8192;      // 128 band rows x 64 words (32 KB)
constexpr int kCap = 96;         // max elements/bucket (mean 16, 12-sigma safe)

static __device__ __forceinline__ float bcastf(float v, int lane) {
    union { float f; int i; } u;
    u.f = v;
    u.i = __builtin_amdgcn_readlane(u.i, lane);
    return u.f;
}

static __device__ __forceinline__ void gload_lds16(const float* g, float* l) {
    __builtin_amdgcn_global_load_lds(
        (const __attribute__((address_space(1))) void*)g,
        (__attribute__((address_space(3))) void*)l, 16, 0, 0);
}

// ---------------- kernel B: one block per bucket; self-service list ----------
__global__ __launch_bounds__(256) void gp_bucket_kernel(
    const float* __restrict__ Uv,
    const float* __restrict__ Vv,
    const float* __restrict__ mean,
    const float* __restrict__ mean_post,
    const float* __restrict__ y,
    const int*   __restrict__ gidx,
    const int*   __restrict__ crow_u,
    const int*   __restrict__ crow_v,
    const float* __restrict__ noise,
    float*       __restrict__ partial)
{
    // band rows r in [64b-63, 64b+64], LDS stride 64 words.
    __shared__ __align__(16) float buf[kBufW];
    __shared__ int   elist[kCap];
    __shared__ int   ecnt;
    __shared__ float cred[4];

    const int tid  = (int)threadIdx.x, lane = tid & 63, wid = tid >> 6;
    const int bid  = (int)blockIdx.x;
    const int b    = ((bid & 7) << 7) | (bid >> 3);   // XCD-chunked (bijective)

    if (tid == 0) ecnt = 0;
    __syncthreads();

    // ---- issue V-band staging (DMA stays in flight during the gidx scan) ----
    if (b >= 1 && b <= kNB - 2) {
        // crow_v[r] = 64r across the band: one contiguous 32KB block.
        // LDS dest must be WAVE-UNIFORM (HW places lane L at dest + 16L).
        const float* src = Vv + 64 * (64 * b - 63);
        #pragma unroll
        for (int k = 0; k < 8; ++k) {
            const int ow = 1024 * k + 256 * wid;      // wave-uniform
            gload_lds16(src + ow + 4 * lane, buf + ow);
        }
    } else if (b == 0) {
        // rows r<0 (words < 63*64=4032) are identity -> zero; plain loads.
        #pragma unroll
        for (int k = 0; k < 8; ++k) {
            const int wd = 1024 * k + 4 * tid;
            float4 val = make_float4(0.0f, 0.0f, 0.0f, 0.0f);
            if (wd >= 4032)
                val = *reinterpret_cast<const float4*>(Vv + (wd - 4032));
            *reinterpret_cast<float4*>(buf + wd) = val;
        }
    } else {
        // b == 1023: band tail, crow_v irregular past r=65473. Per-row stage;
        // consumed columns (<= g <= N-1) always lie within the valid width.
        for (int j = wid; j < 127; j += 4) {
            const int r  = 65409 + j;
            const int rb = crow_v[r];                 // uniform per iteration
            const int w  = (kN - r < 64) ? (kN - r) : 64;
            buf[64 * j + lane] = (lane < w) ? Vv[rb + lane] : 0.0f;
        }
    }

    // ---- find this bucket's elements: scan gidx (64KB, L2-broadcast) ----
    #pragma unroll
    for (int k = 0; k < 16; ++k) {
        const int4 q = reinterpret_cast<const int4*>(gidx)[tid + 256 * k];
        if ((q.x >> 6) == b) { const int p = atomicAdd(&ecnt, 1); if (p < kCap) elist[p] = q.x; }
        if ((q.y >> 6) == b) { const int p = atomicAdd(&ecnt, 1); if (p < kCap) elist[p] = q.y; }
        if ((q.z >> 6) == b) { const int p = atomicAdd(&ecnt, 1); if (p < kCap) elist[p] = q.z; }
        if ((q.w >> 6) == b) { const int p = atomicAdd(&ecnt, 1); if (p < kCap) elist[p] = q.w; }
    }
    __syncthreads();   // drains each wave's DMA (vmcnt) + all LDS appends

    int n = ecnt; if (n > kCap) n = kCap;
    if (n == 0) { if (tid == 0) partial[b] = 0.0f; return; }

    if (tid == 0) {    // deterministic accumulation order (n ~ 16)
        for (int a = 1; a < n; ++a) {
            const int key = elist[a];
            int c = a - 1;
            while (c >= 0 && elist[c] > key) { elist[c + 1] = elist[c]; --c; }
            elist[c + 1] = key;
        }
    }
    __syncthreads();

    const float inv2n = 0.5f / noise[0];
    float accum = 0.0f;
    for (int e = wid; e < n; e += 4) {            // waves share the bucket
        const int g   = elist[e];
        const int off = g - 64 * b;               // 0..63
        const int anc = g - 63 + lane;
        const bool vl = (anc >= 0);               // false only in bucket 0
        const int  L  = (g + 1 < 64) ? (g + 1) : 64;
        const int  ub = (g >= 63) ? (2016 + 64 * (g - 63)) : crow_u[g];

        float uval = 0.0f, md = 0.0f;
        if (vl) {
            uval = Uv[ub + lane - (64 - L)];
            md   = mean[anc] - mean_post[anc];
        }
        const float yv  = y[g];
        const float mpv = mean_post[g];

        const int l = off + lane;                 // this lane's LDS band row
        const float d0 = buf[64 * l];
        const float invd = vl ? (1.0f / d0) : 0.0f;   // mask identity rows

        // v[i] = V_sub[lane][i]/diag = buf[64l + i - lane]/diag; i<lane hits
        // prior-row tail (dead before this lane's residual is consumed).
        const float* vrow = buf + (64 * l - lane);
        float v[64];
        #pragma unroll
        for (int i = 0; i < 64; i += 2) {         // ds_read2 pairs
            const float a0 = vrow[i];
            const float a1 = vrow[i + 1];
            v[i]     = a0 * invd;
            v[i + 1] = a1 * invd;
        }

        float r_e = (lane == 63) ? invd : 0.0f;   // lane 63 always valid
        float r_u = uval * invd;
        float acc_e = 0.0f, acc_u = 0.0f;
        #pragma unroll
        for (int i = 63; i >= 0; --i) {
            const float s_e = bcastf(r_e, i);
            const float s_u = bcastf(r_u, i);
            r_e = fmaf(-v[i], s_e, r_e);
            r_u = fmaf(-v[i], s_u, r_u);
            acc_e = fmaf(s_e, s_e, acc_e);
            acc_u = fmaf(s_u, s_u, acc_u);
        }

        float dot = uval * md;
        #pragma unroll
        for (int m = 1; m < 64; m <<= 1)
            dot += __shfl_xor(dot, m, 64);

        const float ulast  = bcastf(uval, 63);
        const float vfirst = bcastf(d0, 63);      // lane63 row = g
        const float resid  = yv - mpv;
        accum += __logf(ulast) - __logf(vfirst)
               - 0.5f * dot * dot
               - 0.5f * acc_u
               - (resid * resid + acc_e) * inv2n;
    }

    if (lane == 0) cred[wid] = accum;
    __syncthreads();
    if (tid == 0)
        partial[b] = (cred[0] + cred[1]) + (cred[2] + cred[3]);
}

// ---------------- kernel C: final reduce ----------------
__global__ __launch_bounds__(256) void gp_reduce_kernel(
    const float* __restrict__ partial,    // [1024]
    const float* __restrict__ noise,
    float*       __restrict__ out)
{
    __shared__ float ws[4];
    const int t = (int)threadIdx.x;
    const float4 p = reinterpret_cast<const float4*>(partial)[t];  // 256*4=1024
    float a = (p.x + p.y) + (p.z + p.w);
    #pragma unroll
    for (int m = 1; m < 64; m <<= 1)
        a += __shfl_xor(a, m, 64);
    if ((t & 63) == 0) ws[t >> 6] = a;
    __syncthreads();
    if (t == 0) {
        float tot = (ws[0] + ws[1]) + (ws[2] + ws[3]);
        tot += -0.5f * (float)kB * logf(2.0f * 3.14159265358979323846f * noise[0]);
        out[0] = tot;
    }
}

extern "C" void kernel_launch(void* const* d_in, const int* in_sizes, int n_in,
                              void* d_out, int out_size, void* d_ws, size_t ws_size,
                              hipStream_t stream)
{
    const float* Uv        = (const float*)d_in[0];
    const float* Vv        = (const float*)d_in[1];
    const float* mean      = (const float*)d_in[2];
    const float* mean_post = (const float*)d_in[3];
    const float* y         = (const float*)d_in[4];
    const float* noise     = (const float*)d_in[5];
    const int*   gidx      = (const int*)d_in[6];
    const int*   crow_u    = (const int*)d_in[7];
    const int*   crow_v    = (const int*)d_in[8];

    float* partial = (float*)d_ws;   // 1024 floats

    gp_bucket_kernel<<<dim3(kNB), dim3(256), 0, stream>>>(
        Uv, Vv, mean, mean_post, y, gidx, crow_u, crow_v, noise, partial);
    gp_reduce_kernel<<<dim3(1), dim3(256), 0, stream>>>(
        partial, noise, (float*)d_out);
}